// Round 6
// baseline (627.387 us; speedup 1.0000x reference)
//
#include <hip/hip_runtime.h>
#include <stdint.h>

typedef short bf16x8 __attribute__((ext_vector_type(8)));
typedef float f32x4  __attribute__((ext_vector_type(4)));

__device__ __forceinline__ uint32_t bfbits(float f) {
    uint32_t u = __builtin_bit_cast(uint32_t, f);
    u += 0x7FFFu + ((u >> 16) & 1u);   // round-to-nearest-even
    return u >> 16;
}
__device__ __forceinline__ uint32_t pk2(float a, float b) {
    return bfbits(a) | (bfbits(b) << 16);
}

// Wt[t][c][j][ic] = bf16(W[dy][dx][ic][j*4+c]); quadrant c owns oc = j*4+c.
__global__ void wt_kernel(const float* __restrict__ W, short* __restrict__ Wt) {
    int idx = blockIdx.x * 256 + threadIdx.x;      // 9*4*64*64 = 147456
    if (idx >= 147456) return;
    int t  = idx >> 14;
    int r  = idx & 16383;
    int c  = r >> 12;
    int j  = (r >> 6) & 63;
    int ic = r & 63;
    Wt[idx] = (short)bfbits(W[(t * 64 + ic) * 256 + j * 4 + c]);
}

#define NT 6
#define A_SLOT 2176              // shorts per h-row slot: 34 wpos * 64 ic
#define A_SH   (10 * A_SLOT)     // 21760 shorts = 43,520 B (10-row ring)
#define B_SH   (9 * 32 * 64)     // 18432 shorts = 36,864 B
// total 80,384 B -> 2 blocks/CU (16 waves/CU, 4 waves/SIMD)

// Implicit-GEMM conv3x3 + bias + pixel_shuffle quadrant, bf16 MFMA.
// Block: 512 thr = 8 waves, tile = 8 h-rows x 32 w x 32 j (one j-half of a
// quadrant), full K=576 per wave (no reduction). B resident, A ring (10 slots),
// register-staged prefetch. 2 blocks/CU: cross-block TLP hides store drains.
__global__ __launch_bounds__(512, 4) void conv_ps_kernel(
    const float* __restrict__ x, const short* __restrict__ Wt,
    const float* __restrict__ bias, float* __restrict__ out)
{
    __shared__ short smem[A_SH + B_SH];   // 80,384 B
    short* As = smem;
    short* Bs = smem + A_SH;

    const int tid   = threadIdx.x;
    const int lane  = tid & 63;
    const int wv    = tid >> 6;       // which of 8 h-rows in the tile
    const int row_l = lane & 15;
    const int grp   = lane >> 4;
    const int b7    = row_l & 7;

    // XCD-aware bijective swizzle (nwg = 3072 % 8 == 0); (c, jh) innermost so
    // the 8 blocks sharing an x-region land on the same XCD's L2.
    const int raw = blockIdx.x;
    const int lb  = (raw & 7) * 384 + (raw >> 3);
    const int c   = lb & 3;
    const int jh  = (lb >> 2) & 1;
    const int wt6 = (lb >> 3) % 6;
    const int hg  = (lb / 48) & 3;
    const int n   = lb / 192;
    const int w0  = wt6 * 32;
    const int hbase = hg * 48;
    const int q = c & 1, p = (c >> 1) & 1;

    // ---- prologue: B once (write-side XOR swizzle on 16B slots) ----
    {
        const short* wsrc = Wt + c * 4096 + jh * 2048;   // [t][c][j][ic]
        #pragma unroll
        for (int k = 0; k < 5; ++k) {
            int cid = tid + k * 512;               // 0..2303 valid
            if (cid < 2304) {
                int t = cid >> 8, j2 = (cid >> 3) & 31, s = cid & 7;
                bf16x8 v = *(const bf16x8*)(wsrc + t * 16384 + j2 * 64 + s * 8);
                *(bf16x8*)&Bs[t * 2048 + j2 * 64 + ((s ^ (j2 & 7)) << 3)] = v;
            }
        }
    }
    // ---- prologue: A ring, rows hbase-1 .. hbase+8 (10 rows) ----
    #pragma unroll
    for (int k = 0; k < 11; ++k) {
        int cid = tid + k * 512;                   // 0..5439 valid
        if (cid < 5440) {
            int rl   = cid / 544;
            int rem  = cid - rl * 544;
            int wpos = rem >> 4;
            int c4   = rem & 15;
            int r_abs = hbase - 1 + rl;
            int wg    = w0 - 1 + wpos;
            f32x4 v = {0.f, 0.f, 0.f, 0.f};
            if ((unsigned)r_abs < 192u && (unsigned)wg < 192u)
                v = *(const f32x4*)(x + (((size_t)n * 192 + r_abs) * 192 + wg) * 64 + c4 * 4);
            int slot = (hbase + rl) % 10;
            uint2 pr; pr.x = pk2(v[0], v[1]); pr.y = pk2(v[2], v[3]);
            *(uint2*)&As[slot * A_SLOT + wpos * 64 +
                         (((c4 >> 1) ^ (wpos & 7)) << 3) + (c4 & 1) * 4] = pr;
        }
    }
    __syncthreads();

    float bv[2];
    #pragma unroll
    for (int nt = 0; nt < 2; ++nt)
        bv[nt] = bias[(jh * 32 + nt * 16 + row_l) * 4 + c];

    #pragma unroll 1
    for (int it = 0; it < NT; ++it) {
        const int h0 = hbase + it * 8;
        const bool pf = (it < NT - 1);

        // 1. issue next tile's 8 fresh rows (h0+9 .. h0+16) into registers
        f32x4 stg[9];
        if (pf) {
            #pragma unroll
            for (int k = 0; k < 9; ++k) {
                int cid = tid + k * 512;           // 0..4351 valid
                f32x4 v = {0.f, 0.f, 0.f, 0.f};
                if (cid < 4352) {
                    int rl   = cid / 544;
                    int rem  = cid - rl * 544;
                    int wpos = rem >> 4;
                    int c4   = rem & 15;
                    int r_abs = h0 + 9 + rl;
                    int wg    = w0 - 1 + wpos;
                    if (r_abs < 192 && (unsigned)wg < 192u)
                        v = *(const f32x4*)(x + (((size_t)n * 192 + r_abs) * 192 + wg) * 64 + c4 * 4);
                }
                stg[k] = v;
            }
        }

        // 2. acc starts at bias (fused bias add)
        f32x4 acc[2][2];
        #pragma unroll
        for (int i = 0; i < 2; ++i)
            #pragma unroll
            for (int j = 0; j < 2; ++j)
                acc[i][j] = (f32x4){bv[j], bv[j], bv[j], bv[j]};

        // 3. compute: full K=576 for this wave's 32x32 tile, barrier-free
        int sl[3];
        #pragma unroll
        for (int dy = 0; dy < 3; ++dy) sl[dy] = (h0 + wv + dy) % 10;

        #pragma unroll
        for (int dy = 0; dy < 3; ++dy) {
            #pragma unroll
            for (int dx = 0; dx < 3; ++dx) {
                const int t  = dy * 3 + dx;
                const int rd = row_l + dx;
                const int a7 = rd & 7;
                const int aB = sl[dy] * A_SLOT + rd * 64;
                const int bB = t * 2048 + row_l * 64;
                #pragma unroll
                for (int ks = 0; ks < 2; ++ks) {
                    const int kg = ks * 4 + grp;
                    const short* ap = &As[aB + ((kg ^ a7) << 3)];
                    const short* bp = &Bs[bB + ((kg ^ b7) << 3)];
                    bf16x8 af[2], bfr[2];
                    #pragma unroll
                    for (int mt = 0; mt < 2; ++mt) af[mt]  = *(const bf16x8*)(ap + mt * 1024);
                    #pragma unroll
                    for (int nt = 0; nt < 2; ++nt) bfr[nt] = *(const bf16x8*)(bp + nt * 1024);
                    #pragma unroll
                    for (int mt = 0; mt < 2; ++mt)
                        #pragma unroll
                        for (int nt = 0; nt < 2; ++nt)
                            acc[mt][nt] = __builtin_amdgcn_mfma_f32_16x16x32_bf16(
                                af[mt], bfr[nt], acc[mt][nt], 0, 0, 0);
                }
            }
        }

        // 4. stores: quadrant (q,p) + j-half -> each 128B output line single-writer
        {
            const int h = h0 + wv;
            const long rowb = ((long)(n * 384 + 2 * h + q)) * 384;
            #pragma unroll
            for (int mt = 0; mt < 2; ++mt) {
                float* po = out + ((rowb + 2 * (w0 + mt * 16 + grp * 4) + p) * 64
                                   + jh * 32 + row_l);
                #pragma unroll
                for (int nt = 0; nt < 2; ++nt)
                    #pragma unroll
                    for (int jv = 0; jv < 4; ++jv)
                        po[jv * 128 + nt * 16] = acc[mt][nt][jv];
            }
        }

        // 5. rotate ring: barrier, ds_write staged rows, barrier
        if (pf) {
            __syncthreads();   // all waves done reading slots being replaced
            #pragma unroll
            for (int k = 0; k < 9; ++k) {
                int cid = tid + k * 512;
                if (cid < 4352) {
                    int rl   = cid / 544;
                    int rem  = cid - rl * 544;
                    int wpos = rem >> 4;
                    int c4   = rem & 15;
                    int slot = (h0 + 10 + rl) % 10;
                    uint2 pr; pr.x = pk2(stg[k][0], stg[k][1]); pr.y = pk2(stg[k][2], stg[k][3]);
                    *(uint2*)&As[slot * A_SLOT + wpos * 64 +
                                 (((c4 >> 1) ^ (wpos & 7)) << 3) + (c4 & 1) * 4] = pr;
                }
            }
            __syncthreads();   // new rows visible before next tile's reads
        }
    }
}

extern "C" void kernel_launch(void* const* d_in, const int* in_sizes, int n_in,
                              void* d_out, int out_size, void* d_ws, size_t ws_size,
                              hipStream_t stream) {
    const float* x = (const float*)d_in[0];
    const float* W = (const float*)d_in[1];
    const float* b = (const float*)d_in[2];
    float* out = (float*)d_out;
    short* Wt  = (short*)d_ws;   // 9*4*64*64 bf16 = 294,912 B

    hipLaunchKernelGGL(wt_kernel, dim3(576), dim3(256), 0, stream, W, Wt);
    hipLaunchKernelGGL(conv_ps_kernel, dim3(3072), dim3(512), 0, stream, x, Wt, b, out);
}

// Round 7
// 269.119 us; speedup vs baseline: 2.3313x; 2.3313x over previous
//
#include <hip/hip_runtime.h>
#include <stdint.h>

typedef short bf16x8 __attribute__((ext_vector_type(8)));
typedef float f32x4  __attribute__((ext_vector_type(4)));

__device__ __forceinline__ uint32_t bfbits(float f) {
    uint32_t u = __builtin_bit_cast(uint32_t, f);
    u += 0x7FFFu + ((u >> 16) & 1u);   // round-to-nearest-even
    return u >> 16;
}
__device__ __forceinline__ uint32_t pk2(float a, float b) {
    return bfbits(a) | (bfbits(b) << 16);
}

// x (f32) -> xb (bf16), 8 elems/thread/iter, grid-stride
__global__ void xcvt_kernel(const float* __restrict__ x, short* __restrict__ xb, int n8) {
    int i = blockIdx.x * 256 + threadIdx.x;
    const int stride = gridDim.x * 256;
    for (; i < n8; i += stride) {
        f32x4 a = *(const f32x4*)(x + (size_t)i * 8);
        f32x4 b = *(const f32x4*)(x + (size_t)i * 8 + 4);
        uint4 r;
        r.x = pk2(a[0], a[1]); r.y = pk2(a[2], a[3]);
        r.z = pk2(b[0], b[1]); r.w = pk2(b[2], b[3]);
        *(uint4*)(xb + (size_t)i * 8) = r;
    }
}

// Wt[t][c][j][ic] = bf16(W[dy][dx][ic][j*4+c]); quadrant c owns oc = j*4+c.
__global__ void wt_kernel(const float* __restrict__ W, short* __restrict__ Wt) {
    int idx = blockIdx.x * 256 + threadIdx.x;      // 9*4*64*64 = 147456
    if (idx >= 147456) return;
    int t  = idx >> 14;
    int r  = idx & 16383;
    int c  = r >> 12;
    int j  = (r >> 6) & 63;
    int ic = r & 63;
    Wt[idx] = (short)bfbits(W[(t * 64 + ic) * 256 + j * 4 + c]);
}

#define NT 6
#define A_SLOT 2176              // shorts per h-row slot: 34 wpos * 64 ic
#define A_SH   (10 * A_SLOT)     // 43,520 B (10-row ring)
#define B_SH   (9 * 32 * 64)     // 36,864 B
// total 80,384 B -> 2 blocks/CU (16 waves/CU, 4 waves/SIMD)

// Implicit-GEMM conv3x3 + bias + pixel_shuffle quadrant, bf16 MFMA.
// Block: 8 waves, tile = 8 h x 32 w x 32 j, full K=576/wave. B resident,
// A ring + register prefetch. XBF=1: x pre-converted to bf16 (L3-resident).
template <int XBF>
__global__ __launch_bounds__(512, 4) void conv_ps_kernel(
    const float* __restrict__ x, const short* __restrict__ xb,
    const short* __restrict__ Wt, const float* __restrict__ bias,
    float* __restrict__ out)
{
    __shared__ short smem[A_SH + B_SH];   // 80,384 B
    short* As = smem;
    short* Bs = smem + A_SH;

    const int tid   = threadIdx.x;
    const int lane  = tid & 63;
    const int wv    = tid >> 6;       // which of 8 h-rows in the tile
    const int row_l = lane & 15;
    const int grp   = lane >> 4;
    const int b7    = row_l & 7;

    // XCD-aware bijective swizzle (nwg = 3072 % 8 == 0); (c, jh) innermost.
    const int raw = blockIdx.x;
    const int lb  = (raw & 7) * 384 + (raw >> 3);
    const int c   = lb & 3;
    const int jh  = (lb >> 2) & 1;
    const int wt6 = (lb >> 3) % 6;
    const int hg  = (lb / 48) & 3;
    const int n   = lb / 192;
    const int w0  = wt6 * 32;
    const int hbase = hg * 48;
    const int q = c & 1, p = (c >> 1) & 1;

    // ---- prologue: B once (write-side XOR swizzle on 16B slots) ----
    {
        const short* wsrc = Wt + c * 4096 + jh * 2048;   // [t][c][j][ic]
        #pragma unroll
        for (int k = 0; k < 5; ++k) {
            int cid = tid + k * 512;               // 0..2303 valid
            if (cid < 2304) {
                int t = cid >> 8, j2 = (cid >> 3) & 31, s = cid & 7;
                bf16x8 v = *(const bf16x8*)(wsrc + t * 16384 + j2 * 64 + s * 8);
                *(bf16x8*)&Bs[t * 2048 + j2 * 64 + ((s ^ (j2 & 7)) << 3)] = v;
            }
        }
    }
    // ---- prologue: A ring, rows hbase-1 .. hbase+8 (10 rows) ----
    if (XBF) {
        #pragma unroll
        for (int k = 0; k < 6; ++k) {
            int cid = tid + k * 512;               // 0..2719 valid (10*34*8)
            if (cid < 2720) {
                int rl   = cid / 272;
                int rem  = cid - rl * 272;
                int wpos = rem >> 3;
                int g    = rem & 7;
                int r_abs = hbase - 1 + rl;
                int wg    = w0 - 1 + wpos;
                bf16x8 v = {};
                if ((unsigned)r_abs < 192u && (unsigned)wg < 192u)
                    v = *(const bf16x8*)(xb + (((size_t)n * 192 + r_abs) * 192 + wg) * 64 + g * 8);
                int slot = (hbase + rl) % 10;
                *(bf16x8*)&As[slot * A_SLOT + wpos * 64 + ((g ^ (wpos & 7)) << 3)] = v;
            }
        }
    } else {
        #pragma unroll
        for (int k = 0; k < 11; ++k) {
            int cid = tid + k * 512;               // 0..5439 valid
            if (cid < 5440) {
                int rl   = cid / 544;
                int rem  = cid - rl * 544;
                int wpos = rem >> 4;
                int c4   = rem & 15;
                int r_abs = hbase - 1 + rl;
                int wg    = w0 - 1 + wpos;
                f32x4 v = {0.f, 0.f, 0.f, 0.f};
                if ((unsigned)r_abs < 192u && (unsigned)wg < 192u)
                    v = *(const f32x4*)(x + (((size_t)n * 192 + r_abs) * 192 + wg) * 64 + c4 * 4);
                int slot = (hbase + rl) % 10;
                uint2 pr; pr.x = pk2(v[0], v[1]); pr.y = pk2(v[2], v[3]);
                *(uint2*)&As[slot * A_SLOT + wpos * 64 +
                             (((c4 >> 1) ^ (wpos & 7)) << 3) + (c4 & 1) * 4] = pr;
            }
        }
    }
    __syncthreads();

    float bv[2];
    #pragma unroll
    for (int nt = 0; nt < 2; ++nt)
        bv[nt] = bias[(jh * 32 + nt * 16 + row_l) * 4 + c];

    #pragma unroll 1
    for (int it = 0; it < NT; ++it) {
        const int h0 = hbase + it * 8;
        const bool pf = (it < NT - 1);

        // 1. issue next tile's 8 fresh rows (h0+9 .. h0+16) into registers
        bf16x8 stgb[5];
        f32x4  stgf[9];
        if (pf) {
            if (XBF) {
                #pragma unroll
                for (int k = 0; k < 5; ++k) {
                    int cid = tid + k * 512;       // 0..2175 valid (8*34*8)
                    bf16x8 v = {};
                    if (cid < 2176) {
                        int rl   = cid / 272;
                        int rem  = cid - rl * 272;
                        int wpos = rem >> 3;
                        int g    = rem & 7;
                        int r_abs = h0 + 9 + rl;
                        int wg    = w0 - 1 + wpos;
                        if (r_abs < 192 && (unsigned)wg < 192u)
                            v = *(const bf16x8*)(xb + (((size_t)n * 192 + r_abs) * 192 + wg) * 64 + g * 8);
                    }
                    stgb[k] = v;
                }
            } else {
                #pragma unroll
                for (int k = 0; k < 9; ++k) {
                    int cid = tid + k * 512;       // 0..4351 valid
                    f32x4 v = {0.f, 0.f, 0.f, 0.f};
                    if (cid < 4352) {
                        int rl   = cid / 544;
                        int rem  = cid - rl * 544;
                        int wpos = rem >> 4;
                        int c4   = rem & 15;
                        int r_abs = h0 + 9 + rl;
                        int wg    = w0 - 1 + wpos;
                        if (r_abs < 192 && (unsigned)wg < 192u)
                            v = *(const f32x4*)(x + (((size_t)n * 192 + r_abs) * 192 + wg) * 64 + c4 * 4);
                    }
                    stgf[k] = v;
                }
            }
        }

        // 2. acc starts at bias (fused bias add)
        f32x4 acc[2][2];
        #pragma unroll
        for (int i = 0; i < 2; ++i)
            #pragma unroll
            for (int j = 0; j < 2; ++j)
                acc[i][j] = (f32x4){bv[j], bv[j], bv[j], bv[j]};

        // 3. compute: full K=576 for this wave's 32x32 tile, barrier-free
        int sl[3];
        #pragma unroll
        for (int dy = 0; dy < 3; ++dy) sl[dy] = (h0 + wv + dy) % 10;

        #pragma unroll
        for (int dy = 0; dy < 3; ++dy) {
            #pragma unroll
            for (int dx = 0; dx < 3; ++dx) {
                const int t  = dy * 3 + dx;
                const int rd = row_l + dx;
                const int a7 = rd & 7;
                const int aB = sl[dy] * A_SLOT + rd * 64;
                const int bB = t * 2048 + row_l * 64;
                #pragma unroll
                for (int ks = 0; ks < 2; ++ks) {
                    const int kg = ks * 4 + grp;
                    const short* ap = &As[aB + ((kg ^ a7) << 3)];
                    const short* bp = &Bs[bB + ((kg ^ b7) << 3)];
                    bf16x8 af[2], bfr[2];
                    #pragma unroll
                    for (int mt = 0; mt < 2; ++mt) af[mt]  = *(const bf16x8*)(ap + mt * 1024);
                    #pragma unroll
                    for (int nt = 0; nt < 2; ++nt) bfr[nt] = *(const bf16x8*)(bp + nt * 1024);
                    #pragma unroll
                    for (int mt = 0; mt < 2; ++mt)
                        #pragma unroll
                        for (int nt = 0; nt < 2; ++nt)
                            acc[mt][nt] = __builtin_amdgcn_mfma_f32_16x16x32_bf16(
                                af[mt], bfr[nt], acc[mt][nt], 0, 0, 0);
                }
            }
        }

        // 4. stores: quadrant (q,p) + j-half; 128B contiguous per (w) position
        {
            const int h = h0 + wv;
            const long rowb = ((long)(n * 384 + 2 * h + q)) * 384;
            #pragma unroll
            for (int mt = 0; mt < 2; ++mt) {
                float* po = out + ((rowb + 2 * (w0 + mt * 16 + grp * 4) + p) * 64
                                   + jh * 32 + row_l);
                #pragma unroll
                for (int nt = 0; nt < 2; ++nt)
                    #pragma unroll
                    for (int jv = 0; jv < 4; ++jv)
                        po[jv * 128 + nt * 16] = acc[mt][nt][jv];
            }
        }

        // 5. rotate ring: barrier, ds_write staged rows, barrier
        if (pf) {
            __syncthreads();   // all waves done reading slots being replaced
            if (XBF) {
                #pragma unroll
                for (int k = 0; k < 5; ++k) {
                    int cid = tid + k * 512;
                    if (cid < 2176) {
                        int rl   = cid / 272;
                        int rem  = cid - rl * 272;
                        int wpos = rem >> 3;
                        int g    = rem & 7;
                        int slot = (h0 + 10 + rl) % 10;
                        *(bf16x8*)&As[slot * A_SLOT + wpos * 64 + ((g ^ (wpos & 7)) << 3)] = stgb[k];
                    }
                }
            } else {
                #pragma unroll
                for (int k = 0; k < 9; ++k) {
                    int cid = tid + k * 512;
                    if (cid < 4352) {
                        int rl   = cid / 544;
                        int rem  = cid - rl * 544;
                        int wpos = rem >> 4;
                        int c4   = rem & 15;
                        int slot = (h0 + 10 + rl) % 10;
                        uint2 pr; pr.x = pk2(stgf[k][0], stgf[k][1]);
                        pr.y = pk2(stgf[k][2], stgf[k][3]);
                        *(uint2*)&As[slot * A_SLOT + wpos * 64 +
                                     (((c4 >> 1) ^ (wpos & 7)) << 3) + (c4 & 1) * 4] = pr;
                    }
                }
            }
            __syncthreads();   // new rows visible before next tile's reads
        }
    }
}

extern "C" void kernel_launch(void* const* d_in, const int* in_sizes, int n_in,
                              void* d_out, int out_size, void* d_ws, size_t ws_size,
                              hipStream_t stream) {
    const float* x = (const float*)d_in[0];
    const float* W = (const float*)d_in[1];
    const float* b = (const float*)d_in[2];
    float* out = (float*)d_out;

    const size_t xb_bytes = (size_t)16 * 192 * 192 * 64 * 2;   // 75,497,472
    const size_t wt_bytes = 294912;

    if (ws_size >= xb_bytes + wt_bytes) {
        short* xb = (short*)d_ws;
        short* Wt = (short*)((char*)d_ws + xb_bytes);
        hipLaunchKernelGGL(xcvt_kernel, dim3(2048), dim3(256), 0, stream, x, xb, 4718592);
        hipLaunchKernelGGL(wt_kernel, dim3(576), dim3(256), 0, stream, W, Wt);
        hipLaunchKernelGGL((conv_ps_kernel<1>), dim3(3072), dim3(512), 0, stream,
                           x, xb, Wt, b, out);
    } else {
        short* Wt = (short*)d_ws;
        hipLaunchKernelGGL(wt_kernel, dim3(576), dim3(256), 0, stream, W, Wt);
        hipLaunchKernelGGL((conv_ps_kernel<0>), dim3(3072), dim3(512), 0, stream,
                           x, (const short*)nullptr, Wt, b, out);
    }
}